// Round 7
// baseline (158.494 us; speedup 1.0000x reference)
//
#include <hip/hip_runtime.h>
#include <hip/hip_bf16.h>
#include <math.h>

#define B_   4
#define C_   256
#define H_   56
#define W_   56
#define HW_  3136
#define OC1  128
#define NT   49
#define NP   64          // padded logit count
#define HP_  68          // 56 + 2*6 padded
#define M_TOT 12544      // B_*HW_
#define NSL  14          // K-split slices: 7 tap-rows x 2 cc-halves (4 cc each)

typedef __attribute__((ext_vector_type(8))) short bf16x8;
typedef __attribute__((ext_vector_type(4))) float f32x4;

typedef const __attribute__((address_space(1))) unsigned int gu32;
typedef __attribute__((address_space(3))) unsigned int lu32;

// ===========================================================================
// FAST PATH: fused-weight bf16 MFMA implicit GEMM (conv2 folded into conv1)
// logits = conv(x, Wf) + cb,  Wf[l,c,tap] = sum_oc W2[l,oc]*W1[oc,c,tap]
// xp2 layout: [cc 8][b 4][hp 68][wp 68][ci 32] bf16   (validated R4-R14)
// wfb layout: [tap 49][cc 8][ntile 4][lane 64][j 8] bf16 fragment order
// kpart: bf16 [slice 14][m 12544][n 64]
// R21 post-mortem: full-K fusion forces every block to read ALL of wfb
// (448 x 1.6 MB = 717 MB L2 ~ 21 us floor) -> fusion reverted.
// R22 diagnosis: in R17/R20/R21 the per-step B GLOBAL loads share the vmcnt
// counter with the A global_load_lds DMAs; vmcnt retires in issue order, so
// the compiler's precise B-waits forced all older DMA issues to complete ->
// the "full-phase prefetch" never existed. Fix (m201 pattern): B is ALSO
// DMA-staged into LDS and consumed via ds_read (lgkmcnt) -> inner loop has
// zero global loads; A-DMA stays in flight the whole phase.
// ===========================================================================

// Merged prep kernel (validated R13/R14; R18: float4 x-row loads in xpack).
// Blocks [0,2176): xpack (x -> xp2). Blocks [2176,2568): wfuse.
__global__ __launch_bounds__(256) void prep_kernel(const float* __restrict__ x,
                                                   const float* __restrict__ W1,
                                                   const float* __restrict__ W2,
                                                   const float* __restrict__ b1,
                                                   const float* __restrict__ b2,
                                                   __hip_bfloat16* __restrict__ xp,
                                                   __hip_bfloat16* __restrict__ wfb,
                                                   float* __restrict__ cb)
{
    __shared__ char smem[49408];         // union: wfuse 49,408 B / xpack 4,352 B
    int bid = blockIdx.x;
    int tid = threadIdx.x;

    if (bid < 2176) {
        // ---------------- xpack branch ------------------------------------
        short* tile = (short*)smem;      // [wp][ci] = 68*32 shorts
        int cc = bid / (B_ * HP_);
        int r  = bid - cc * (B_ * HP_);
        int b  = r / HP_;
        int hp = r - b * HP_;
        int h  = hp - 6;

        if (h < 0 || h >= H_) {
            for (int idx = tid; idx < HP_ * 32; idx += 256) tile[idx] = 0;
        } else {
            int ci = tid >> 3;
            int wg = tid & 7;
            const float* xr = x + ((size_t)(b * C_ + cc * 32 + ci) * H_ + h) * W_;
            const f32x4* xr4 = (const f32x4*)xr;   // row base is 224B-multiple
            {
                f32x4 v0 = xr4[wg];
                #pragma unroll
                for (int q = 0; q < 4; ++q) {
                    __hip_bfloat16 t = __float2bfloat16(v0[q]);
                    tile[(wg * 4 + q + 6) * 32 + ci] = *(short*)&t;
                }
            }
            if (wg < 6) {
                f32x4 v1 = xr4[wg + 8];
                #pragma unroll
                for (int q = 0; q < 4; ++q) {
                    __hip_bfloat16 t = __float2bfloat16(v1[q]);
                    tile[((wg + 8) * 4 + q + 6) * 32 + ci] = *(short*)&t;
                }
            }
            for (int idx = tid; idx < 384; idx += 256) {
                int wp = idx >> 5;
                int wz = (wp < 6) ? wp : (wp + 56);
                tile[wz * 32 + (idx & 31)] = 0;
            }
        }
        __syncthreads();
        short* outp = (short*)xp + ((size_t)((cc * B_ + b) * HP_ + hp) * HP_) * 32;
        for (int idx = tid; idx < 272; idx += 256)
            *(bf16x8*)(outp + idx * 8) = *(bf16x8*)(tile + idx * 8);
    } else {
        // ---------------- wfuse branch (validated) -------------------------
        float* sW2 = (float*)smem;               // [n][oc] stride 129 = 33,024 B
        float* sW1 = (float*)(smem + 33024);     // [oc][ci] = 16,384 B
        int q2  = bid - 2176;                    // 0..391
        int tap = q2 >> 3;                       // 0..48
        int cc  = q2 & 7;                        // 0..7

        for (int idx = tid; idx < NP * 128; idx += 256) {
            int n = idx >> 7, oc = idx & 127;
            sW2[n * 129 + oc] = (n < NT) ? W2[n * 128 + oc] : 0.0f;
        }
        for (int idx = tid; idx < 128 * 32; idx += 256) {
            int oc = idx >> 5, ci = idx & 31;
            sW1[idx] = W1[((size_t)(oc * C_ + cc * 32 + ci)) * NT + tap];
        }
        __syncthreads();

        int ntile = tid >> 6;
        int l     = tid & 63;
        int n     = ntile * 16 + (l & 15);
        int q     = l >> 4;

        float acc[8] = {0,0,0,0,0,0,0,0};
        for (int oc = 0; oc < 128; ++oc) {
            float w2 = sW2[n * 129 + oc];
            const float* r = &sW1[oc * 32 + q * 8];
            #pragma unroll
            for (int j = 0; j < 8; ++j)
                acc[j] += w2 * r[j];
        }

        short pk[8];
        #pragma unroll
        for (int j = 0; j < 8; ++j) {
            __hip_bfloat16 v = __float2bfloat16(acc[j]);
            pk[j] = *(short*)&v;
        }
        short* dst = (short*)wfb + ((size_t)(tap * 8 + cc) * 4 + ntile) * 512 + l * 8;
        *(bf16x8*)dst = *(bf16x8*)pk;

        if (tap == 0 && cc == 0 && tid < 64) {
            float a = 0.0f;
            if (tid < NT) {
                a = b2[tid];
                for (int oc = 0; oc < 128; ++oc)
                    a += sW2[tid * 129 + oc] * b1[oc];
            }
            cb[tid] = a;
        }
    }
}

// R22: conv with decoupled counters. A: double-buffered DMA (vmcnt). B: the
// phase's 28 KB wfb slab DMA-staged into a single LDS buffer, consumed via
// ds_read_b128 (lgkmcnt). Inner loop: zero global loads -> compiler emits
// lgkm-only waits; A-DMA stays in flight across the whole phase.
// Phase p: {vmcnt(0) [A(p), phase-covered]; barrier} -> STAGE_B(p),
// STAGE_A(p+1) -> {vmcnt(6) [own 7 B retired, A(p+1) in flight]; barrier}
// -> 7 lgkm-pure j-steps. LDS 80,896 B -> 2 blocks/CU.
__global__ __launch_bounds__(256, 2) void conv1_mfma13(const __hip_bfloat16* __restrict__ xp,
                                                       const __hip_bfloat16* __restrict__ wfb,
                                                       __hip_bfloat16* __restrict__ kpart)
{
    __shared__ char sAst[2][26112];       // A double buffer (6 rows x 4352 B)
    __shared__ char sBst[28672];          // B phase slab: 7 taps x 4 nt x 1 KB

    const int bid = blockIdx.x;
    const int g   = bid & 7;              // presumed XCD (round-robin dispatch)
    const int kk  = bid >> 3;             // 0..97
    const int s   = (g * 49) >> 3;
    const int cnt = (((g + 1) * 49) >> 3) - s;   // 6 or 7
    const int slice = kk / cnt;           // 0..13 valid
    if (slice >= NSL) return;
    const int mblk = s + (kk - slice * cnt);
    const int m0   = mblk * 256;
    const int i    = slice >> 1;          // tap row 0..6
    const int ch   = slice & 1;           // cc half: cc in [ch*4, ch*4+4)
    const int cc0  = ch * 4;

    const int tid  = threadIdx.x;
    const int lane = tid & 63;
    const int wid  = tid >> 6;            // waveM: wave owns rows m0+wid*64..+63
    const int quad = lane >> 4, l16 = lane & 15;

    const char*  xpb = (const char*)xp;
    const char*  wbb = (const char*)wfb;

    // ---- block-uniform staging geometry (6 global rows gr0..gr0+5) --------
    const int gr0 = m0 / 56;              // first (b,h) row index
    const int b0  = gr0 / 56;
    const int h0  = gr0 - b0 * 56;
    const int kr_ = (b0 + 1) * 56 - gr0;  // rows before the b-split
    const int krows  = kr_ < 6 ? kr_ : 6;
    const int bytesA = krows * 4352;
    const int bytesB = 26112 - bytesA;
    const long relA  = ((long)(b0 * HP_ + h0 + 2 * i)) * 4352;      // byte off in cc slab
    const long relB  = ((long)((b0 + 1) * HP_ + 2 * i)) * 4352;     // h=0 rows of b0+1
    const int nA = (bytesA >> 10) + ((bytesA & 1023) ? 1 : 0);
    const int nB = (bytesB >> 10) + ((bytesB & 1023) ? 1 : 0);
    const int nTot = nA + nB;             // <= 28 wave-issues per phase
    const long CC_BYTES = (long)B_ * HP_ * HP_ * 64;   // 1,183,744 B per cc
    const long lw16 = (long)lane * 16;

    // ---- per-thread A-fragment LDS byte offsets ---------------------------
    int lbase[4];
    #pragma unroll
    for (int mt = 0; mt < 4; ++mt) {
        int m  = m0 + wid * 64 + mt * 16 + l16;
        int gr = m / 56;
        int w  = m - gr * 56;
        lbase[mt] = (gr - gr0) * 4352 + w * 64 + quad * 16;
    }

    f32x4 acc[4][4];
    #pragma unroll
    for (int a = 0; a < 4; ++a)
        #pragma unroll
        for (int b2 = 0; b2 < 4; ++b2) acc[a][b2] = (f32x4){0.f, 0.f, 0.f, 0.f};

    bf16x8 Ar[2][4], Br[2][4];

    // A-stage for phase pp (cc = cc0+pp) into buffer pp&1; waves split issues.
#define STAGEA(pp)                                                             \
    {                                                                          \
        const char* sA_ = xpb + (long)(cc0 + (pp)) * CC_BYTES + relA;          \
        const char* sB_ = xpb + (long)(cc0 + (pp)) * CC_BYTES + relB;          \
        char* dbase = &sAst[(pp) & 1][0];                                      \
        for (int q = wid; q < nTot; q += 4) {                                  \
            const char* sp; int d;                                             \
            if (q < nA) {                                                      \
                int off = q << 10;                                             \
                if (off + 1024 > bytesA) off = bytesA - 1024;                  \
                sp = sA_ + off; d = off;                                       \
            } else {                                                           \
                int off = (q - nA) << 10;                                      \
                if (off + 1024 > bytesB) off = bytesB - 1024;                  \
                sp = sB_ + off; d = bytesA + off;                              \
            }                                                                  \
            __builtin_amdgcn_global_load_lds(                                  \
                (gu32*)(sp + lw16), (lu32*)(dbase + d), 16, 0, 0);             \
        }                                                                      \
    }

    // B-stage for phase pp: 28 x 1 KB chunks, chunk q -> (j=q>>2, nt=q&3);
    // src chunk = wfb[(((i*7+j)*8 + cc0+pp)*4 + nt) * 1024 B]; dst = q*1024.
#define STAGEB(pp)                                                             \
    {                                                                          \
        for (int q = wid; q < 28; q += 4) {                                    \
            const char* sp = wbb +                                             \
                ((((long)(i * 7 + (q >> 2)) * 8 + cc0 + (pp)) * 4              \
                  + (q & 3)) << 10);                                           \
            __builtin_amdgcn_global_load_lds(                                  \
                (gu32*)(sp + lw16), (lu32*)(&sBst[q << 10]), 16, 0, 0);        \
        }                                                                      \
    }

#define LDSB(slot, j)                                                          \
    { _Pragma("unroll")                                                        \
      for (int nt = 0; nt < 4; ++nt)                                           \
          Br[slot][nt] = *(const bf16x8*)(&sBst[((((j) << 2) + nt) << 10)]     \
                                          + lw16); }

#define LDSA(slot, pp, j)                                                      \
    { const char* ab = &sAst[(pp) & 1][0];                                     \
      _Pragma("unroll")                                                        \
      for (int mt = 0; mt < 4; ++mt)                                           \
          Ar[slot][mt] = *(const bf16x8*)(ab + lbase[mt] + (j) * 128); }

    // prologue: issue phase-0 A stage; p=0's barrier#1 drains it (once)
    STAGEA(0)

    #pragma unroll
    for (int p = 0; p < 4; ++p) {
        // barrier#1: A(p) complete (full-phase covered for p>0); all waves'
        // reads of sBst (phase p-1) and sAst[(p+1)&1] (phase p-1) retired.
        asm volatile("s_waitcnt vmcnt(0)" ::: "memory");
        __builtin_amdgcn_s_barrier();

        STAGEB(p)                          // 7 B issues per wave (oldest)
        if (p < 3) STAGEA(p + 1)           // 6-7 A issues (newest, in flight)

        // counted wait: own 7 B retired; A(p+1) stays outstanding. p=3: no
        // A was issued -> full drain of the 7 B issues.
        if (p < 3) { asm volatile("s_waitcnt vmcnt(6)" ::: "memory"); }
        else       { asm volatile("s_waitcnt vmcnt(0)" ::: "memory"); }
        __builtin_amdgcn_s_barrier();      // barrier#2: all waves' B visible

        LDSB(0, 0)
        LDSB(1, 1)
        LDSA(0, p, 0)

        #pragma unroll
        for (int j = 0; j < 7; ++j) {
            const int cs = j & 1;
            if (j < 6) LDSA((j + 1) & 1, p, j + 1)

            __builtin_amdgcn_s_setprio(1);
            #pragma unroll
            for (int mt = 0; mt < 4; ++mt)
                #pragma unroll
                for (int nt = 0; nt < 4; ++nt)
                    acc[mt][nt] = __builtin_amdgcn_mfma_f32_16x16x32_bf16(
                        Ar[cs][mt], Br[cs][nt], acc[mt][nt], 0, 0, 0);
            __builtin_amdgcn_s_setprio(0);

            if (j + 2 <= 6) LDSB(cs, j + 2)
        }
    }
#undef STAGEA
#undef STAGEB
#undef LDSB
#undef LDSA

    // Store bf16: C/D layout col(n)=lane&15, row(m)=quad*4+reg (validated)
    #pragma unroll
    for (int mt = 0; mt < 4; ++mt) {
        int mrow = m0 + wid * 64 + mt * 16 + quad * 4;
        #pragma unroll
        for (int nt = 0; nt < 4; ++nt) {
            int n = nt * 16 + l16;
            __hip_bfloat16* dst = kpart + ((long)slice * M_TOT + mrow) * NP + n;
            #pragma unroll
            for (int r = 0; r < 4; ++r)
                dst[(long)r * NP] = __float2bfloat16(acc[mt][nt][r]);
        }
    }
}

// R18: 8 pixels/wave vectorized fold (validated).
__global__ __launch_bounds__(256) void attn_fold3(const unsigned short* __restrict__ kpart,
                                                  const float* __restrict__ cb,
                                                  float* __restrict__ attnP)
{
    int tid  = threadIdx.x;
    int wid  = tid >> 6;
    int lane = tid & 63;
    int p0   = (blockIdx.x * 4 + wid) * 8;    // first of 8 pixels for this wave
    int sub  = lane >> 3;                     // pixel = p0 + sub
    int k    = lane & 7;                      // n = k*8 + j

    const short* kp = (const short*)kpart + (long)p0 * NP + lane * 8;
    float a8[8] = {0,0,0,0,0,0,0,0};
    #pragma unroll
    for (int sp = 0; sp < NSL; ++sp) {
        bf16x8 v = *(const bf16x8*)(kp + (long)sp * M_TOT * NP);
        #pragma unroll
        for (int j = 0; j < 8; ++j) {
            unsigned int u = (unsigned int)(unsigned short)v[j] << 16;
            a8[j] += __uint_as_float(u);
        }
    }

    const f32x4* cb4 = (const f32x4*)cb;
    f32x4 c0 = cb4[k * 2], c1 = cb4[k * 2 + 1];
    float lg[8];
    #pragma unroll
    for (int j = 0; j < 8; ++j) {
        float c = (j < 4) ? c0[j & 3] : c1[j & 3];
        lg[j] = (k * 8 + j < NT) ? (a8[j] + c) : -INFINITY;
    }
    float mx = lg[0];
    #pragma unroll
    for (int j = 1; j < 8; ++j) mx = fmaxf(mx, lg[j]);
    mx = fmaxf(mx, __shfl_xor(mx, 1, 64));
    mx = fmaxf(mx, __shfl_xor(mx, 2, 64));
    mx = fmaxf(mx, __shfl_xor(mx, 4, 64));

    float e[8]; float sum = 0.f;
    #pragma unroll
    for (int j = 0; j < 8; ++j) {
        e[j] = (k * 8 + j < NT) ? __expf(lg[j] - mx) : 0.f;
        sum += e[j];
    }
    sum += __shfl_xor(sum, 1, 64);
    sum += __shfl_xor(sum, 2, 64);
    sum += __shfl_xor(sum, 4, 64);
    float inv = 1.0f / sum;

    float* op = attnP + (long)(p0 + sub) * NT + k * 8;
    #pragma unroll
    for (int j = 0; j < 8; ++j)
        if (k * 8 + j < NT) op[j] = e[j] * inv;
}

// R18: out kernel with float4 staging and ONE barrier (validated).
__global__ __launch_bounds__(256) void out_kernel5(const float* __restrict__ x,
                                                   const float* __restrict__ attnP,
                                                   float* __restrict__ out)
{
    __shared__ float sX[7 * 4 * HP_ * 4]; // [i][cg4][wp][c4] 30.5 KB
    __shared__ float sA[56 * NT];         // [w][l] 10.7 KB

    int bid = blockIdx.x;                // < 3584
    int g   = bid & 7;                   // presumed XCD
    int s   = bid >> 3;                  // 0..447
    int bh  = g * 28 + (s % 28);         // 28 bh-rows per XCD slot
    int cg  = s / 28;                    // 0..15
    int b   = bh / H_;
    int h   = bh - b * H_;
    int c0  = cg * 16;
    int tid = threadIdx.x;

    // halo zero: cols wp in {0..5} u {62..67}, all 28 (i,cgr) rows (f32x4)
    {
        f32x4* sX4 = (f32x4*)sX;
        for (int idx = tid; idx < 28 * 12; idx += 256) {
            int row = idx / 12, t = idx - row * 12;
            int wp  = (t < 6) ? t : (t + 56);
            sX4[row * HP_ + wp] = (f32x4){0.f, 0.f, 0.f, 0.f};
        }
    }
    // attn stage: 686 float4 (base is 16B-aligned: 196*56 = 16*686)
    {
        const f32x4* ap4 = (const f32x4*)(attnP + ((size_t)(b * HW_) + h * W_) * NT);
        f32x4* sA4 = (f32x4*)sA;
        for (int idx = tid; idx < 686; idx += 256)
            sA4[idx] = ap4[idx];
    }
    // x stage: 16 ch x 14 float4 lanes; zero-fill invalid rows (no pre-zero)
    {
        int c  = tid >> 4;
        int wg = tid & 15;
        if (wg < 14) {
            const float* xc = x + (size_t)(b * C_ + c0 + c) * HW_;
            int cgr = c >> 2, ce = c & 3;
            #pragma unroll
            for (int i = 0; i < 7; ++i) {
                int ih = h + 2 * i - 6;
                f32x4 v = (f32x4){0.f, 0.f, 0.f, 0.f};
                if (ih >= 0 && ih < H_)
                    v = *(const f32x4*)(xc + (size_t)ih * W_ + wg * 4);
                float* dst = &sX[(((i * 4 + cgr) * HP_) + (wg * 4 + 6)) * 4 + ce];
                dst[0]  = v.x; dst[4]  = v.y;
                dst[8]  = v.z; dst[12] = v.w;
            }
        }
    }
    __syncthreads();

    int lane = tid & 63;
    int wid  = tid >> 6;                 // wave -> channels c0+wid*4 .. +3
    int w    = lane;
    bool active = (w < W_);
    int wc = active ? w : (W_ - 1);

    float aR[NT];
    #pragma unroll
    for (int l = 0; l < NT; ++l)
        aR[l] = sA[wc * NT + l];

    f32x4 acc = (f32x4){0.f, 0.f, 0.f, 0.f};
    #pragma unroll
    for (int i = 0; i < 7; ++i) {
        const float* sXi = &sX[(i * 4 + wid) * HP_ * 4];
        #pragma unroll
        for (int j = 0; j < 7; ++j) {
            f32x4 xv = *(const f32x4*)&sXi[(wc + 2 * j) * 4];
            float a = aR[i * 7 + j];
            acc.x += a * xv.x; acc.y += a * xv.y;
            acc.z += a * xv.z; acc.w += a * xv.w;
        }
    }

    if (active) {
        size_t o = ((size_t)(b * C_ + c0 + wid * 4)) * HW_ + h * W_ + w;
        out[o + 0 * HW_] = acc.x;
        out[o + 1 * HW_] = acc.y;
        out[o + 2 * HW_] = acc.z;
        out[o + 3 * HW_] = acc.w;
    }
}

// ===========================================================================
// FALLBACK PATH (R1, proven): used only if ws_size < fast-path need
// ===========================================================================
__global__ __launch_bounds__(256) void wt_kernel(const float* __restrict__ W1,
                                                 float* __restrict__ wT)
{
    int idx = blockIdx.x * 256 + threadIdx.x;
    int oc = idx & 127;
    int ct = idx >> 7;
    wT[idx] = W1[oc * (C_ * NT) + ct];
}

__global__ __launch_bounds__(256) void conv1_kernel(const float* __restrict__ x,
                                                    const float* __restrict__ wT,
                                                    const float* __restrict__ b1,
                                                    float* __restrict__ k)
{
    int tid = threadIdx.x;
    int w   = tid & 63;
    int ty  = tid >> 6;
    int h   = blockIdx.x * 4 + ty;
    int oc0 = blockIdx.y * 8;
    int b   = blockIdx.z;

    const float* xb = x + (size_t)b * C_ * HW_;
    float acc[8] = {0.f,0.f,0.f,0.f,0.f,0.f,0.f,0.f};

    for (int i = 0; i < 7; ++i) {
        int ih = h + 2 * i - 6;
        if (ih < 0 || ih >= H_) continue;
        for (int j = 0; j < 7; ++j) {
            int iw = w + 2 * j - 6;
            bool v  = (iw >= 0) && (iw < W_);
            float m = v ? 1.0f : 0.0f;
            const float* xr = xb + ih * W_ + (v ? iw : 0);
            const float* wr = wT + (size_t)(i * 7 + j) * OC1 + oc0;
            #pragma unroll 4
            for (int c = 0; c < C_; ++c) {
                float xv = m * xr[(size_t)c * HW_];
                const float4 w0 = *(const float4*)(wr + (size_t)c * NT * OC1);
                const float4 w1 = *(const float4*)(wr + (size_t)c * NT * OC1 + 4);
                acc[0] += xv * w0.x; acc[1] += xv * w0.y;
                acc[2] += xv * w0.z; acc[3] += xv * w0.w;
                acc[4] += xv * w1.x; acc[5] += xv * w1.y;
                acc[6] += xv * w1.z; acc[7] += xv * w1.w;
            }
        }
    }
    if (w < W_) {
        size_t o = ((size_t)(b * OC1 + oc0)) * HW_ + h * W_ + w;
        #pragma unroll
        for (int q = 0; q < 8; ++q)
            k[o + (size_t)q * HW_] = acc[q] + b1[oc0 + q];
    }
}

__global__ __launch_bounds__(256) void attn_kernel(const float* __restrict__ kin,
                                                   const float* __restrict__ W2,
                                                   const float* __restrict__ b2,
                                                   float* __restrict__ attn)
{
    __shared__ float sW2[128 * 49];
    int tid = threadIdx.x;
    for (int idx = tid; idx < 128 * 49; idx += 256) {
        int c = idx / 49, l = idx - c * 49;
        sW2[idx] = W2[l * 128 + c];
    }
    __syncthreads();

    int wid  = tid >> 6;
    int lane = tid & 63;
    int pix  = blockIdx.x * 4 + wid;
    int b    = pix / HW_;
    int hw   = pix - b * HW_;
    int l    = (lane < 49) ? lane : 0;

    const float* kb = kin + (size_t)b * OC1 * HW_ + hw;
    float acc = b2[l];
    #pragma unroll 8
    for (int c = 0; c < 128; ++c)
        acc += kb[(size_t)c * HW_] * sW2[c * 49 + l];

    float logit = (lane < 49) ? acc : -INFINITY;
    float mx = logit;
    for (int s = 32; s > 0; s >>= 1) mx = fmaxf(mx, __shfl_xor(mx, s, 64));
    float e = (lane < 49) ? __expf(logit - mx) : 0.0f;
    float sum = e;
    for (int s = 32; s > 0; s >>= 1) sum += __shfl_xor(sum, s, 64);
    if (lane < 49)
        attn[((size_t)b * NT + lane) * HW_ + hw] = e / sum;
}

__global__ __launch_bounds__(256) void out_kernel(const float* __restrict__ x,
                                                  const float* __restrict__ attn,
                                                  float* __restrict__ out)
{
    int idx = blockIdx.x * 256 + threadIdx.x;
    int w  = idx % 56;
    int t  = idx / 56;
    int h  = t % 56;
    int t2 = t / 56;
    int c  = t2 & 255;
    int b  = t2 >> 8;

    const float* xb = x + (size_t)(b * C_ + c) * HW_;
    const float* ab = attn + (size_t)b * NT * HW_ + h * W_ + w;

    float acc = 0.f;
    #pragma unroll
    for (int i = 0; i < 7; ++i) {
        int ih = h + 2 * i - 6;
        bool hv = (ih >= 0) && (ih < H_);
        #pragma unroll
        for (int j = 0; j < 7; ++j) {
            int iw = w + 2 * j - 6;
            bool v  = hv && (iw >= 0) && (iw < W_);
            float m = v ? 1.0f : 0.0f;
            int off = v ? (ih * W_ + iw) : 0;
            acc += (m * xb[off]) * ab[(size_t)(i * 7 + j) * HW_];
        }
    }
    out[idx] = acc;
}

// ===========================================================================
extern "C" void kernel_launch(void* const* d_in, const int* in_sizes, int n_in,
                              void* d_out, int out_size, void* d_ws, size_t ws_size,
                              hipStream_t stream)
{
    const float* x  = (const float*)d_in[0];
    const float* W1 = (const float*)d_in[1];
    const float* b1 = (const float*)d_in[2];
    const float* W2 = (const float*)d_in[3];
    const float* b2 = (const float*)d_in[4];
    float* out = (float*)d_out;

    // fast-path ws layout (bytes)
    const size_t xp_b    = (size_t)B_ * HP_ * HP_ * 256 * 2;        //  9,469,952
    const size_t wfb_b   = (size_t)NT * 8 * 4 * 64 * 8 * 2;         //  1,605,632
    const size_t kpart_b = (size_t)NSL * M_TOT * NP * 2;            // 22,478,848 (bf16)
    const size_t attn_b  = (size_t)M_TOT * NT * 4;                  //  2,458,624
    const size_t cb_b    = 256;
    const size_t need = xp_b + wfb_b + kpart_b + attn_b + cb_b;     // ~36.0 MB

    if (ws_size >= need) {
        char* base = (char*)d_ws;
        __hip_bfloat16* xp    = (__hip_bfloat16*)base;
        __hip_bfloat16* wfb   = (__hip_bfloat16*)(base + xp_b);
        __hip_bfloat16* kpart = (__hip_bfloat16*)(base + xp_b + wfb_b);
        float* attnP = (float*)(base + xp_b + wfb_b + kpart_b);
        float* cb    = (float*)(base + xp_b + wfb_b + kpart_b + attn_b);

        prep_kernel  <<<2568, 256, 0, stream>>>(x, W1, W2, b1, b2, xp, wfb, cb);
        conv1_mfma13 <<<784, 256, 0, stream>>>(xp, wfb, kpart);
        attn_fold3   <<<392, 256, 0, stream>>>((const unsigned short*)kpart, cb, attnP);
        out_kernel5  <<<3584, 256, 0, stream>>>(x, attnP, out);
    } else {
        // R1 fallback (~14.6 MB)
        float* wT   = (float*)d_ws;
        float* kbuf = wT + 1605632;
        float* attn = kbuf + 1605632;
        wt_kernel   <<<6272, 256, 0, stream>>>(W1, wT);
        conv1_kernel<<<dim3(14, 16, 4), 256, 0, stream>>>(x, wT, b1, kbuf);
        attn_kernel <<<3136, 256, 0, stream>>>(kbuf, W2, b2, attn);
        out_kernel  <<<12544, 256, 0, stream>>>(x, attn, out);
    }
}

// Round 8
// 158.308 us; speedup vs baseline: 1.0012x; 1.0012x over previous
//
#include <hip/hip_runtime.h>
#include <hip/hip_bf16.h>
#include <math.h>

#define B_   4
#define C_   256
#define H_   56
#define W_   56
#define HW_  3136
#define OC1  128
#define NT   49
#define NP   64          // padded logit count
#define HP_  68          // 56 + 2*6 padded
#define M_TOT 12544      // B_*HW_
#define NSL  14          // K-split slices: 7 tap-rows x 2 cc-halves (4 cc each)

typedef __attribute__((ext_vector_type(8))) short bf16x8;
typedef __attribute__((ext_vector_type(4))) float f32x4;

typedef const __attribute__((address_space(1))) unsigned int gu32;
typedef __attribute__((address_space(3))) unsigned int lu32;

// ===========================================================================
// FAST PATH: fused-weight bf16 MFMA implicit GEMM (conv2 folded into conv1)
// logits = conv(x, Wf) + cb,  Wf[l,c,tap] = sum_oc W2[l,oc]*W1[oc,c,tap]
// xp2 layout: [cc 8][b 4][hp 68][wp 68][ci 32] bf16   (validated R4-R14)
// wfb layout: [tap 49][cc 8][ntile 4][lane 64][j 8] bf16 fragment order
// kpart: bf16 [slice 14][m 12544][n 64]
// R22 post-mortem: B-via-LDS fixed the vmcnt collision but cost more than it
// earned (28 serial B-DMA chunks + 2 blocks/CU): +2.8 us. Reverted to R20.
// R23: the collision is fixed by ORDERING alone. R20 issued STAGE(p+1) at
// phase top; the first j-step's B-wait (in-order vmcnt) then forced all 26
// older DMA ops to retire -> zero prefetch cover, every phase = DMA latency
// + consume. Now: j=0..4 first (all 7 B-loadsets issued, waits shallow),
// THEN STAGE(p+1) (sched_barrier-pinned; DMA = newest ops, B-waits for j5/j6
// leave it outstanding), then j=5..6. DMA drains at next phase-top vmcnt(0)
// with j5+j6 + inter-block TLP as cover.
// ===========================================================================

// Merged prep kernel (validated R13/R14; R18: float4 x-row loads in xpack).
// Blocks [0,2176): xpack (x -> xp2). Blocks [2176,2568): wfuse.
__global__ __launch_bounds__(256) void prep_kernel(const float* __restrict__ x,
                                                   const float* __restrict__ W1,
                                                   const float* __restrict__ W2,
                                                   const float* __restrict__ b1,
                                                   const float* __restrict__ b2,
                                                   __hip_bfloat16* __restrict__ xp,
                                                   __hip_bfloat16* __restrict__ wfb,
                                                   float* __restrict__ cb)
{
    __shared__ char smem[49408];         // union: wfuse 49,408 B / xpack 4,352 B
    int bid = blockIdx.x;
    int tid = threadIdx.x;

    if (bid < 2176) {
        // ---------------- xpack branch ------------------------------------
        short* tile = (short*)smem;      // [wp][ci] = 68*32 shorts
        int cc = bid / (B_ * HP_);
        int r  = bid - cc * (B_ * HP_);
        int b  = r / HP_;
        int hp = r - b * HP_;
        int h  = hp - 6;

        if (h < 0 || h >= H_) {
            for (int idx = tid; idx < HP_ * 32; idx += 256) tile[idx] = 0;
        } else {
            int ci = tid >> 3;
            int wg = tid & 7;
            const float* xr = x + ((size_t)(b * C_ + cc * 32 + ci) * H_ + h) * W_;
            const f32x4* xr4 = (const f32x4*)xr;   // row base is 224B-multiple
            {
                f32x4 v0 = xr4[wg];
                #pragma unroll
                for (int q = 0; q < 4; ++q) {
                    __hip_bfloat16 t = __float2bfloat16(v0[q]);
                    tile[(wg * 4 + q + 6) * 32 + ci] = *(short*)&t;
                }
            }
            if (wg < 6) {
                f32x4 v1 = xr4[wg + 8];
                #pragma unroll
                for (int q = 0; q < 4; ++q) {
                    __hip_bfloat16 t = __float2bfloat16(v1[q]);
                    tile[((wg + 8) * 4 + q + 6) * 32 + ci] = *(short*)&t;
                }
            }
            for (int idx = tid; idx < 384; idx += 256) {
                int wp = idx >> 5;
                int wz = (wp < 6) ? wp : (wp + 56);
                tile[wz * 32 + (idx & 31)] = 0;
            }
        }
        __syncthreads();
        short* outp = (short*)xp + ((size_t)((cc * B_ + b) * HP_ + hp) * HP_) * 32;
        for (int idx = tid; idx < 272; idx += 256)
            *(bf16x8*)(outp + idx * 8) = *(bf16x8*)(tile + idx * 8);
    } else {
        // ---------------- wfuse branch (validated) -------------------------
        float* sW2 = (float*)smem;               // [n][oc] stride 129 = 33,024 B
        float* sW1 = (float*)(smem + 33024);     // [oc][ci] = 16,384 B
        int q2  = bid - 2176;                    // 0..391
        int tap = q2 >> 3;                       // 0..48
        int cc  = q2 & 7;                        // 0..7

        for (int idx = tid; idx < NP * 128; idx += 256) {
            int n = idx >> 7, oc = idx & 127;
            sW2[n * 129 + oc] = (n < NT) ? W2[n * 128 + oc] : 0.0f;
        }
        for (int idx = tid; idx < 128 * 32; idx += 256) {
            int oc = idx >> 5, ci = idx & 31;
            sW1[idx] = W1[((size_t)(oc * C_ + cc * 32 + ci)) * NT + tap];
        }
        __syncthreads();

        int ntile = tid >> 6;
        int l     = tid & 63;
        int n     = ntile * 16 + (l & 15);
        int q     = l >> 4;

        float acc[8] = {0,0,0,0,0,0,0,0};
        for (int oc = 0; oc < 128; ++oc) {
            float w2 = sW2[n * 129 + oc];
            const float* r = &sW1[oc * 32 + q * 8];
            #pragma unroll
            for (int j = 0; j < 8; ++j)
                acc[j] += w2 * r[j];
        }

        short pk[8];
        #pragma unroll
        for (int j = 0; j < 8; ++j) {
            __hip_bfloat16 v = __float2bfloat16(acc[j]);
            pk[j] = *(short*)&v;
        }
        short* dst = (short*)wfb + ((size_t)(tap * 8 + cc) * 4 + ntile) * 512 + l * 8;
        *(bf16x8*)dst = *(bf16x8*)pk;

        if (tap == 0 && cc == 0 && tid < 64) {
            float a = 0.0f;
            if (tid < NT) {
                a = b2[tid];
                for (int oc = 0; oc < 128; ++oc)
                    a += sW2[tid * 129 + oc] * b1[oc];
            }
            cb[tid] = a;
        }
    }
}

// R23: R20 body, STAGE(p+1) moved to AFTER the last B-load issue (end of
// j=4). B-waits for j0..j4 are shallow (no DMA outstanding); B-waits for
// j5/j6 count the DMA as newer (vmcnt>=26) and leave it in flight; the DMA
// drains at the next phase-top vmcnt(0) with j5+j6 as cover + 3-blocks/CU
// TLP. sched_barrier(0) pins the STAGE position against hoisting.
__global__ __launch_bounds__(256, 3) void conv1_mfma14(const __hip_bfloat16* __restrict__ xp,
                                                       const __hip_bfloat16* __restrict__ wfb,
                                                       __hip_bfloat16* __restrict__ kpart)
{
    __shared__ char sAst[2][26112];       // A double buffer (6 rows x 4352 B)

    const int bid = blockIdx.x;
    const int g   = bid & 7;              // presumed XCD (round-robin dispatch)
    const int kk  = bid >> 3;             // 0..97
    const int s   = (g * 49) >> 3;
    const int cnt = (((g + 1) * 49) >> 3) - s;   // 6 or 7
    const int slice = kk / cnt;           // 0..13 valid
    if (slice >= NSL) return;
    const int mblk = s + (kk - slice * cnt);
    const int m0   = mblk * 256;
    const int i    = slice >> 1;          // tap row 0..6
    const int ch   = slice & 1;           // cc half: cc in [ch*4, ch*4+4)
    const int cc0  = ch * 4;

    const int tid  = threadIdx.x;
    const int lane = tid & 63;
    const int wid  = tid >> 6;            // waveM: wave owns rows m0+wid*64..+63
    const int quad = lane >> 4, l16 = lane & 15;

    const char*  xpb = (const char*)xp;
    const short* wbs = (const short*)wfb;

    // ---- block-uniform staging geometry (6 global rows gr0..gr0+5) --------
    const int gr0 = m0 / 56;              // first (b,h) row index
    const int b0  = gr0 / 56;
    const int h0  = gr0 - b0 * 56;
    const int kr_ = (b0 + 1) * 56 - gr0;  // rows before the b-split
    const int krows  = kr_ < 6 ? kr_ : 6;
    const int bytesA = krows * 4352;
    const int bytesB = 26112 - bytesA;
    const long relA  = ((long)(b0 * HP_ + h0 + 2 * i)) * 4352;      // byte off in cc slab
    const long relB  = ((long)((b0 + 1) * HP_ + 2 * i)) * 4352;     // h=0 rows of b0+1
    const int nA = (bytesA >> 10) + ((bytesA & 1023) ? 1 : 0);
    const int nB = (bytesB >> 10) + ((bytesB & 1023) ? 1 : 0);
    const int nTot = nA + nB;             // <= 28 wave-issues per phase
    const long CC_BYTES = (long)B_ * HP_ * HP_ * 64;   // 1,183,744 B per cc

    // ---- per-thread A-fragment LDS byte offsets ---------------------------
    int lbase[4];
    #pragma unroll
    for (int mt = 0; mt < 4; ++mt) {
        int m  = m0 + wid * 64 + mt * 16 + l16;
        int gr = m / 56;
        int w  = m - gr * 56;
        lbase[mt] = (gr - gr0) * 4352 + w * 64 + quad * 16;
    }

    f32x4 acc[4][4];
    #pragma unroll
    for (int a = 0; a < 4; ++a)
        #pragma unroll
        for (int b2 = 0; b2 < 4; ++b2) acc[a][b2] = (f32x4){0.f, 0.f, 0.f, 0.f};

    bf16x8 Ar[2][4], Br[2][4];

    // A-stage for phase pp (cc = cc0+pp) into buffer pp&1; waves split issues.
#define STAGE(pp)                                                              \
    {                                                                          \
        const char* sA_ = xpb + (long)(cc0 + (pp)) * CC_BYTES + relA;          \
        const char* sB_ = xpb + (long)(cc0 + (pp)) * CC_BYTES + relB;          \
        char* dbase = &sAst[(pp) & 1][0];                                      \
        for (int q = wid; q < nTot; q += 4) {                                  \
            const char* sp; int d;                                             \
            if (q < nA) {                                                      \
                int off = q << 10;                                             \
                if (off + 1024 > bytesA) off = bytesA - 1024;                  \
                sp = sA_ + off; d = off;                                       \
            } else {                                                           \
                int off = (q - nA) << 10;                                      \
                if (off + 1024 > bytesB) off = bytesB - 1024;                  \
                sp = sB_ + off; d = bytesA + off;                              \
            }                                                                  \
            __builtin_amdgcn_global_load_lds(                                  \
                (gu32*)(sp + (long)lane * 16),                                 \
                (lu32*)(dbase + d), 16, 0, 0);                                 \
        }                                                                      \
    }

#define LOADB(slot, cc, j)                                                     \
    { _Pragma("unroll")                                                        \
      for (int nt = 0; nt < 4; ++nt)                                           \
          Br[slot][nt] = *(const bf16x8*)(wbs +                                \
              ((((long)(i * 7 + (j)) * 8 + (cc)) * 4 + nt) << 9) +             \
              (long)lane * 8); }

#define LDSA(slot, pp, j)                                                      \
    { const char* ab = &sAst[(pp) & 1][0];                                     \
      _Pragma("unroll")                                                        \
      for (int mt = 0; mt < 4; ++mt)                                           \
          Ar[slot][mt] = *(const bf16x8*)(ab + lbase[mt] + (j) * 128); }

#define MFMAS(cs)                                                              \
    {                                                                          \
        __builtin_amdgcn_s_setprio(1);                                         \
        _Pragma("unroll")                                                      \
        for (int mt = 0; mt < 4; ++mt)                                         \
            _Pragma("unroll")                                                  \
            for (int nt = 0; nt < 4; ++nt)                                     \
                acc[mt][nt] = __builtin_amdgcn_mfma_f32_16x16x32_bf16(         \
                    Ar[cs][mt], Br[cs][nt], acc[mt][nt], 0, 0, 0);             \
        __builtin_amdgcn_s_setprio(0);                                         \
    }

    // prologue: issue phase-0 stage; p=0's top-sync drains it (uncovered, 1x)
    STAGE(0)

    #pragma unroll
    for (int p = 0; p < 4; ++p) {
        const int cc = cc0 + p;

        // phase-top sync: A(p) DMA drains here (covered by prev phase's
        // j5/j6 + TLP); all waves' reads of buf[(p-1)&1] retired.
        asm volatile("s_waitcnt vmcnt(0)" ::: "memory");
        __builtin_amdgcn_s_barrier();

        LOADB(0, cc, 0)
        LOADB(1, cc, 1)
        LDSA(0, p, 0)

        // j = 0..4: all remaining B-loads issued; waits stay shallow (no
        // DMA outstanding in this window).
        #pragma unroll
        for (int j = 0; j < 5; ++j) {
            const int cs = j & 1;
            LDSA((j + 1) & 1, p, j + 1)
            MFMAS(cs)
            LOADB(cs, cc, j + 2)          // slots alternate; j+2 in 2..6
        }

        // all 7 B-loadsets are now OLDER than the DMA about to be issued ->
        // j5/j6's B-waits (vmcnt>=26) leave the DMA in flight.
        __builtin_amdgcn_sched_barrier(0);
        if (p < 3) STAGE(p + 1)

        // j = 5, 6
        LDSA(0, p, 6)
        MFMAS(1)                           // j=5 uses Br[1] (loaded at j=3)
        MFMAS(0)                           // j=6 uses Br[0] (loaded at j=4)
    }
#undef STAGE
#undef LOADB
#undef LDSA
#undef MFMAS

    // Store bf16: C/D layout col(n)=lane&15, row(m)=quad*4+reg (validated)
    #pragma unroll
    for (int mt = 0; mt < 4; ++mt) {
        int mrow = m0 + wid * 64 + mt * 16 + quad * 4;
        #pragma unroll
        for (int nt = 0; nt < 4; ++nt) {
            int n = nt * 16 + l16;
            __hip_bfloat16* dst = kpart + ((long)slice * M_TOT + mrow) * NP + n;
            #pragma unroll
            for (int r = 0; r < 4; ++r)
                dst[(long)r * NP] = __float2bfloat16(acc[mt][nt][r]);
        }
    }
}

// R18: 8 pixels/wave vectorized fold (validated).
__global__ __launch_bounds__(256) void attn_fold3(const unsigned short* __restrict__ kpart,
                                                  const float* __restrict__ cb,
                                                  float* __restrict__ attnP)
{
    int tid  = threadIdx.x;
    int wid  = tid >> 6;
    int lane = tid & 63;
    int p0   = (blockIdx.x * 4 + wid) * 8;    // first of 8 pixels for this wave
    int sub  = lane >> 3;                     // pixel = p0 + sub
    int k    = lane & 7;                      // n = k*8 + j

    const short* kp = (const short*)kpart + (long)p0 * NP + lane * 8;
    float a8[8] = {0,0,0,0,0,0,0,0};
    #pragma unroll
    for (int sp = 0; sp < NSL; ++sp) {
        bf16x8 v = *(const bf16x8*)(kp + (long)sp * M_TOT * NP);
        #pragma unroll
        for (int j = 0; j < 8; ++j) {
            unsigned int u = (unsigned int)(unsigned short)v[j] << 16;
            a8[j] += __uint_as_float(u);
        }
    }

    const f32x4* cb4 = (const f32x4*)cb;
    f32x4 c0 = cb4[k * 2], c1 = cb4[k * 2 + 1];
    float lg[8];
    #pragma unroll
    for (int j = 0; j < 8; ++j) {
        float c = (j < 4) ? c0[j & 3] : c1[j & 3];
        lg[j] = (k * 8 + j < NT) ? (a8[j] + c) : -INFINITY;
    }
    float mx = lg[0];
    #pragma unroll
    for (int j = 1; j < 8; ++j) mx = fmaxf(mx, lg[j]);
    mx = fmaxf(mx, __shfl_xor(mx, 1, 64));
    mx = fmaxf(mx, __shfl_xor(mx, 2, 64));
    mx = fmaxf(mx, __shfl_xor(mx, 4, 64));

    float e[8]; float sum = 0.f;
    #pragma unroll
    for (int j = 0; j < 8; ++j) {
        e[j] = (k * 8 + j < NT) ? __expf(lg[j] - mx) : 0.f;
        sum += e[j];
    }
    sum += __shfl_xor(sum, 1, 64);
    sum += __shfl_xor(sum, 2, 64);
    sum += __shfl_xor(sum, 4, 64);
    float inv = 1.0f / sum;

    float* op = attnP + (long)(p0 + sub) * NT + k * 8;
    #pragma unroll
    for (int j = 0; j < 8; ++j)
        if (k * 8 + j < NT) op[j] = e[j] * inv;
}

// R18: out kernel with float4 staging and ONE barrier (validated).
__global__ __launch_bounds__(256) void out_kernel5(const float* __restrict__ x,
                                                   const float* __restrict__ attnP,
                                                   float* __restrict__ out)
{
    __shared__ float sX[7 * 4 * HP_ * 4]; // [i][cg4][wp][c4] 30.5 KB
    __shared__ float sA[56 * NT];         // [w][l] 10.7 KB

    int bid = blockIdx.x;                // < 3584
    int g   = bid & 7;                   // presumed XCD
    int s   = bid >> 3;                  // 0..447
    int bh  = g * 28 + (s % 28);         // 28 bh-rows per XCD slot
    int cg  = s / 28;                    // 0..15
    int b   = bh / H_;
    int h   = bh - b * H_;
    int c0  = cg * 16;
    int tid = threadIdx.x;

    // halo zero: cols wp in {0..5} u {62..67}, all 28 (i,cgr) rows (f32x4)
    {
        f32x4* sX4 = (f32x4*)sX;
        for (int idx = tid; idx < 28 * 12; idx += 256) {
            int row = idx / 12, t = idx - row * 12;
            int wp  = (t < 6) ? t : (t + 56);
            sX4[row * HP_ + wp] = (f32x4){0.f, 0.f, 0.f, 0.f};
        }
    }
    // attn stage: 686 float4 (base is 16B-aligned: 196*56 = 16*686)
    {
        const f32x4* ap4 = (const f32x4*)(attnP + ((size_t)(b * HW_) + h * W_) * NT);
        f32x4* sA4 = (f32x4*)sA;
        for (int idx = tid; idx < 686; idx += 256)
            sA4[idx] = ap4[idx];
    }
    // x stage: 16 ch x 14 float4 lanes; zero-fill invalid rows (no pre-zero)
    {
        int c  = tid >> 4;
        int wg = tid & 15;
        if (wg < 14) {
            const float* xc = x + (size_t)(b * C_ + c0 + c) * HW_;
            int cgr = c >> 2, ce = c & 3;
            #pragma unroll
            for (int i = 0; i < 7; ++i) {
                int ih = h + 2 * i - 6;
                f32x4 v = (f32x4){0.f, 0.f, 0.f, 0.f};
                if (ih >= 0 && ih < H_)
                    v = *(const f32x4*)(xc + (size_t)ih * W_ + wg * 4);
                float* dst = &sX[(((i * 4 + cgr) * HP_) + (wg * 4 + 6)) * 4 + ce];
                dst[0]  = v.x; dst[4]  = v.y;
                dst[8]  = v.z; dst[12] = v.w;
            }
        }
    }
    __syncthreads();

    int lane = tid & 63;
    int wid  = tid >> 6;                 // wave -> channels c0+wid*4 .. +3
    int w    = lane;
    bool active = (w < W_);
    int wc = active ? w : (W_ - 1);

    float aR[NT];
    #pragma unroll
    for (int l = 0; l < NT; ++l)
        aR[l] = sA[wc * NT + l];

    f32x4 acc = (f32x4){0.f, 0.f, 0.f, 0.f};
    #pragma unroll
    for (int i = 0; i < 7; ++i) {
        const float* sXi = &sX[(i * 4 + wid) * HP_ * 4];
        #pragma unroll
        for (int j = 0; j < 7; ++j) {
            f32x4 xv = *(const f32x4*)&sXi[(wc + 2 * j) * 4];
            float a = aR[i * 7 + j];
            acc.x += a * xv.x; acc.y += a * xv.y;
            acc.z += a * xv.z; acc.w += a * xv.w;
        }
    }

    if (active) {
        size_t o = ((size_t)(b * C_ + c0 + wid * 4)) * HW_ + h * W_ + w;
        out[o + 0 * HW_] = acc.x;
        out[o + 1 * HW_] = acc.y;
        out[o + 2 * HW_] = acc.z;
        out[o + 3 * HW_] = acc.w;
    }
}

// ===========================================================================
// FALLBACK PATH (R1, proven): used only if ws_size < fast-path need
// ===========================================================================
__global__ __launch_bounds__(256) void wt_kernel(const float* __restrict__ W1,
                                                 float* __restrict__ wT)
{
    int idx = blockIdx.x * 256 + threadIdx.x;
    int oc = idx & 127;
    int ct = idx >> 7;
    wT[idx] = W1[oc * (C_ * NT) + ct];
}

__global__ __launch_bounds__(256) void conv1_kernel(const float* __restrict__ x,
                                                    const float* __restrict__ wT,
                                                    const float* __restrict__ b1,
                                                    float* __restrict__ k)
{
    int tid = threadIdx.x;
    int w   = tid & 63;
    int ty  = tid >> 6;
    int h   = blockIdx.x * 4 + ty;
    int oc0 = blockIdx.y * 8;
    int b   = blockIdx.z;

    const float* xb = x + (size_t)b * C_ * HW_;
    float acc[8] = {0.f,0.f,0.f,0.f,0.f,0.f,0.f,0.f};

    for (int i = 0; i < 7; ++i) {
        int ih = h + 2 * i - 6;
        if (ih < 0 || ih >= H_) continue;
        for (int j = 0; j < 7; ++j) {
            int iw = w + 2 * j - 6;
            bool v  = (iw >= 0) && (iw < W_);
            float m = v ? 1.0f : 0.0f;
            const float* xr = xb + ih * W_ + (v ? iw : 0);
            const float* wr = wT + (size_t)(i * 7 + j) * OC1 + oc0;
            #pragma unroll 4
            for (int c = 0; c < C_; ++c) {
                float xv = m * xr[(size_t)c * HW_];
                const float4 w0 = *(const float4*)(wr + (size_t)c * NT * OC1);
                const float4 w1 = *(const float4*)(wr + (size_t)c * NT * OC1 + 4);
                acc[0] += xv * w0.x; acc[1] += xv * w0.y;
                acc[2] += xv * w0.z; acc[3] += xv * w0.w;
                acc[4] += xv * w1.x; acc[5] += xv * w1.y;
                acc[6] += xv * w1.z; acc[7] += xv * w1.w;
            }
        }
    }
    if (w < W_) {
        size_t o = ((size_t)(b * OC1 + oc0)) * HW_ + h * W_ + w;
        #pragma unroll
        for (int q = 0; q < 8; ++q)
            k[o + (size_t)q * HW_] = acc[q] + b1[oc0 + q];
    }
}

__global__ __launch_bounds__(256) void attn_kernel(const float* __restrict__ kin,
                                                   const float* __restrict__ W2,
                                                   const float* __restrict__ b2,
                                                   float* __restrict__ attn)
{
    __shared__ float sW2[128 * 49];
    int tid = threadIdx.x;
    for (int idx = tid; idx < 128 * 49; idx += 256) {
        int c = idx / 49, l = idx - c * 49;
        sW2[idx] = W2[l * 128 + c];
    }
    __syncthreads();

    int wid  = tid >> 6;
    int lane = tid & 63;
    int pix  = blockIdx.x * 4 + wid;
    int b    = pix / HW_;
    int hw   = pix - b * HW_;
    int l    = (lane < 49) ? lane : 0;

    const float* kb = kin + (size_t)b * OC1 * HW_ + hw;
    float acc = b2[l];
    #pragma unroll 8
    for (int c = 0; c < 128; ++c)
        acc += kb[(size_t)c * HW_] * sW2[c * 49 + l];

    float logit = (lane < 49) ? acc : -INFINITY;
    float mx = logit;
    for (int s = 32; s > 0; s >>= 1) mx = fmaxf(mx, __shfl_xor(mx, s, 64));
    float e = (lane < 49) ? __expf(logit - mx) : 0.0f;
    float sum = e;
    for (int s = 32; s > 0; s >>= 1) sum += __shfl_xor(sum, s, 64);
    if (lane < 49)
        attn[((size_t)b * NT + lane) * HW_ + hw] = e / sum;
}

__global__ __launch_bounds__(256) void out_kernel(const float* __restrict__ x,
                                                  const float* __restrict__ attn,
                                                  float* __restrict__ out)
{
    int idx = blockIdx.x * 256 + threadIdx.x;
    int w  = idx % 56;
    int t  = idx / 56;
    int h  = t % 56;
    int t2 = t / 56;
    int c  = t2 & 255;
    int b  = t2 >> 8;

    const float* xb = x + (size_t)(b * C_ + c) * HW_;
    const float* ab = attn + (size_t)b * NT * HW_ + h * W_ + w;

    float acc = 0.f;
    #pragma unroll
    for (int i = 0; i < 7; ++i) {
        int ih = h + 2 * i - 6;
        bool hv = (ih >= 0) && (ih < H_);
        #pragma unroll
        for (int j = 0; j < 7; ++j) {
            int iw = w + 2 * j - 6;
            bool v  = hv && (iw >= 0) && (iw < W_);
            float m = v ? 1.0f : 0.0f;
            int off = v ? (ih * W_ + iw) : 0;
            acc += (m * xb[off]) * ab[(size_t)(i * 7 + j) * HW_];
        }
    }
    out[idx] = acc;
}

// ===========================================================================
extern "C" void kernel_launch(void* const* d_in, const int* in_sizes, int n_in,
                              void* d_out, int out_size, void* d_ws, size_t ws_size,
                              hipStream_t stream)
{
    const float* x  = (const float*)d_in[0];
    const float* W1 = (const float*)d_in[1];
    const float* b1 = (const float*)d_in[2];
    const float* W2 = (const float*)d_in[3];
    const float* b2 = (const float*)d_in[4];
    float* out = (float*)d_out;

    // fast-path ws layout (bytes)
    const size_t xp_b    = (size_t)B_ * HP_ * HP_ * 256 * 2;        //  9,469,952
    const size_t wfb_b   = (size_t)NT * 8 * 4 * 64 * 8 * 2;         //  1,605,632
    const size_t kpart_b = (size_t)NSL * M_TOT * NP * 2;            // 22,478,848 (bf16)
    const size_t attn_b  = (size_t)M_TOT * NT * 4;                  //  2,458,624
    const size_t cb_b    = 256;
    const size_t need = xp_b + wfb_b + kpart_b + attn_b + cb_b;     // ~36.0 MB

    if (ws_size >= need) {
        char* base = (char*)d_ws;
        __hip_bfloat16* xp    = (__hip_bfloat16*)base;
        __hip_bfloat16* wfb   = (__hip_bfloat16*)(base + xp_b);
        __hip_bfloat16* kpart = (__hip_bfloat16*)(base + xp_b + wfb_b);
        float* attnP = (float*)(base + xp_b + wfb_b + kpart_b);
        float* cb    = (float*)(base + xp_b + wfb_b + kpart_b + attn_b);

        prep_kernel  <<<2568, 256, 0, stream>>>(x, W1, W2, b1, b2, xp, wfb, cb);
        conv1_mfma14 <<<784, 256, 0, stream>>>(xp, wfb, kpart);
        attn_fold3   <<<392, 256, 0, stream>>>((const unsigned short*)kpart, cb, attnP);
        out_kernel5  <<<3584, 256, 0, stream>>>(x, attnP, out);
    } else {
        // R1 fallback (~14.6 MB)
        float* wT   = (float*)d_ws;
        float* kbuf = wT + 1605632;
        float* attn = kbuf + 1605632;
        wt_kernel   <<<6272, 256, 0, stream>>>(W1, wT);
        conv1_kernel<<<dim3(14, 16, 4), 256, 0, stream>>>(x, wT, b1, kbuf);
        attn_kernel <<<3136, 256, 0, stream>>>(kbuf, W2, b2, attn);
        out_kernel  <<<12544, 256, 0, stream>>>(x, attn, out);
    }
}

// Round 9
// 154.507 us; speedup vs baseline: 1.0258x; 1.0246x over previous
//
#include <hip/hip_runtime.h>
#include <hip/hip_bf16.h>
#include <math.h>

#define B_   4
#define C_   256
#define H_   56
#define W_   56
#define HW_  3136
#define OC1  128
#define NT   49
#define NP   64          // padded logit count
#define HP_  68          // 56 + 2*6 padded
#define M_TOT 12544      // B_*HW_
#define NSL  14          // K-split slices: 7 tap-rows x 2 cc-halves (4 cc each)

typedef __attribute__((ext_vector_type(8))) short bf16x8;
typedef __attribute__((ext_vector_type(4))) float f32x4;

typedef const __attribute__((address_space(1))) unsigned int gu32;
typedef __attribute__((address_space(3))) unsigned int lu32;

// ===========================================================================
// FAST PATH: fused-weight bf16 MFMA implicit GEMM (conv2 folded into conv1)
// logits = conv(x, Wf) + cb,  Wf[l,c,tap] = sum_oc W2[l,oc]*W1[oc,c,tap]
// xp2 layout: [cc 8][b 4][hp 68][wp 68][ci 32] bf16   (validated R4-R14)
// wfb layout: [tap 49][cc 8][ntile 4][lane 64][j 8] bf16 fragment order
// kpart: bf16 [slice 14][m 12544][n 64]
// R24: REVERT to R20 (best measured, 155.7 us). The vmcnt-ordering theory
// was falsified three ways (R20 barrier placement: null; R22 B-via-LDS:
// -2.8; R23 issue-order inversion: -2.6). conv at ~32 us = 628 TF effective
// on a skinny N=64 GEMM (25% of dense MFMA peak) is its practical floor at
// this shape. ~86 us of e2e is harness workspace-fill inside the timed
// window (2 x 256 MB at ~6.2 TB/s, constant across rounds).
// ===========================================================================

// Merged prep kernel (validated R13/R14; R18: float4 x-row loads in xpack).
// Blocks [0,2176): xpack (x -> xp2). Blocks [2176,2568): wfuse.
__global__ __launch_bounds__(256) void prep_kernel(const float* __restrict__ x,
                                                   const float* __restrict__ W1,
                                                   const float* __restrict__ W2,
                                                   const float* __restrict__ b1,
                                                   const float* __restrict__ b2,
                                                   __hip_bfloat16* __restrict__ xp,
                                                   __hip_bfloat16* __restrict__ wfb,
                                                   float* __restrict__ cb)
{
    __shared__ char smem[49408];         // union: wfuse 49,408 B / xpack 4,352 B
    int bid = blockIdx.x;
    int tid = threadIdx.x;

    if (bid < 2176) {
        // ---------------- xpack branch ------------------------------------
        short* tile = (short*)smem;      // [wp][ci] = 68*32 shorts
        int cc = bid / (B_ * HP_);
        int r  = bid - cc * (B_ * HP_);
        int b  = r / HP_;
        int hp = r - b * HP_;
        int h  = hp - 6;

        if (h < 0 || h >= H_) {
            for (int idx = tid; idx < HP_ * 32; idx += 256) tile[idx] = 0;
        } else {
            int ci = tid >> 3;
            int wg = tid & 7;
            const float* xr = x + ((size_t)(b * C_ + cc * 32 + ci) * H_ + h) * W_;
            const f32x4* xr4 = (const f32x4*)xr;   // row base is 224B-multiple
            {
                f32x4 v0 = xr4[wg];
                #pragma unroll
                for (int q = 0; q < 4; ++q) {
                    __hip_bfloat16 t = __float2bfloat16(v0[q]);
                    tile[(wg * 4 + q + 6) * 32 + ci] = *(short*)&t;
                }
            }
            if (wg < 6) {
                f32x4 v1 = xr4[wg + 8];
                #pragma unroll
                for (int q = 0; q < 4; ++q) {
                    __hip_bfloat16 t = __float2bfloat16(v1[q]);
                    tile[((wg + 8) * 4 + q + 6) * 32 + ci] = *(short*)&t;
                }
            }
            for (int idx = tid; idx < 384; idx += 256) {
                int wp = idx >> 5;
                int wz = (wp < 6) ? wp : (wp + 56);
                tile[wz * 32 + (idx & 31)] = 0;
            }
        }
        __syncthreads();
        short* outp = (short*)xp + ((size_t)((cc * B_ + b) * HP_ + hp) * HP_) * 32;
        for (int idx = tid; idx < 272; idx += 256)
            *(bf16x8*)(outp + idx * 8) = *(bf16x8*)(tile + idx * 8);
    } else {
        // ---------------- wfuse branch (validated) -------------------------
        float* sW2 = (float*)smem;               // [n][oc] stride 129 = 33,024 B
        float* sW1 = (float*)(smem + 33024);     // [oc][ci] = 16,384 B
        int q2  = bid - 2176;                    // 0..391
        int tap = q2 >> 3;                       // 0..48
        int cc  = q2 & 7;                        // 0..7

        for (int idx = tid; idx < NP * 128; idx += 256) {
            int n = idx >> 7, oc = idx & 127;
            sW2[n * 129 + oc] = (n < NT) ? W2[n * 128 + oc] : 0.0f;
        }
        for (int idx = tid; idx < 128 * 32; idx += 256) {
            int oc = idx >> 5, ci = idx & 31;
            sW1[idx] = W1[((size_t)(oc * C_ + cc * 32 + ci)) * NT + tap];
        }
        __syncthreads();

        int ntile = tid >> 6;
        int l     = tid & 63;
        int n     = ntile * 16 + (l & 15);
        int q     = l >> 4;

        float acc[8] = {0,0,0,0,0,0,0,0};
        for (int oc = 0; oc < 128; ++oc) {
            float w2 = sW2[n * 129 + oc];
            const float* r = &sW1[oc * 32 + q * 8];
            #pragma unroll
            for (int j = 0; j < 8; ++j)
                acc[j] += w2 * r[j];
        }

        short pk[8];
        #pragma unroll
        for (int j = 0; j < 8; ++j) {
            __hip_bfloat16 v = __float2bfloat16(acc[j]);
            pk[j] = *(short*)&v;
        }
        short* dst = (short*)wfb + ((size_t)(tap * 8 + cc) * 4 + ntile) * 512 + l * 8;
        *(bf16x8*)dst = *(bf16x8*)pk;

        if (tap == 0 && cc == 0 && tid < 64) {
            float a = 0.0f;
            if (tid < NT) {
                a = b2[tid];
                for (int oc = 0; oc < 128; ++oc)
                    a += sW2[tid * 129 + oc] * b1[oc];
            }
            cb[tid] = a;
        }
    }
}

// R20 (best measured): R17 body with the phase sync at phase TOP: {asm
// vmcnt(0); raw s_barrier} BEFORE STAGE(p+1). Buffer safety: all reads of
// buf[(p-1)&1] retired before the barrier; STAGE(p+1) overwrites exactly
// that buffer.
__global__ __launch_bounds__(256, 3) void conv1_mfma12(const __hip_bfloat16* __restrict__ xp,
                                                       const __hip_bfloat16* __restrict__ wfb,
                                                       __hip_bfloat16* __restrict__ kpart)
{
    __shared__ char sAst[2][26112];       // A double buffer (6 rows x 4352 B)

    const int bid = blockIdx.x;
    const int g   = bid & 7;              // presumed XCD (round-robin dispatch)
    const int kk  = bid >> 3;             // 0..97
    const int s   = (g * 49) >> 3;
    const int cnt = (((g + 1) * 49) >> 3) - s;   // 6 or 7
    const int slice = kk / cnt;           // 0..13 valid
    if (slice >= NSL) return;
    const int mblk = s + (kk - slice * cnt);
    const int m0   = mblk * 256;
    const int i    = slice >> 1;          // tap row 0..6
    const int ch   = slice & 1;           // cc half: cc in [ch*4, ch*4+4)
    const int cc0  = ch * 4;

    const int tid  = threadIdx.x;
    const int lane = tid & 63;
    const int wid  = tid >> 6;            // waveM: wave owns rows m0+wid*64..+63
    const int quad = lane >> 4, l16 = lane & 15;

    const char*  xpb = (const char*)xp;
    const short* wbs = (const short*)wfb;

    // ---- block-uniform staging geometry (6 global rows gr0..gr0+5) --------
    const int gr0 = m0 / 56;              // first (b,h) row index
    const int b0  = gr0 / 56;
    const int h0  = gr0 - b0 * 56;
    const int kr_ = (b0 + 1) * 56 - gr0;  // rows before the b-split
    const int krows  = kr_ < 6 ? kr_ : 6;
    const int bytesA = krows * 4352;
    const int bytesB = 26112 - bytesA;
    const long relA  = ((long)(b0 * HP_ + h0 + 2 * i)) * 4352;      // byte off in cc slab
    const long relB  = ((long)((b0 + 1) * HP_ + 2 * i)) * 4352;     // h=0 rows of b0+1
    const int nA = (bytesA >> 10) + ((bytesA & 1023) ? 1 : 0);
    const int nB = (bytesB >> 10) + ((bytesB & 1023) ? 1 : 0);
    const int nTot = nA + nB;             // <= 28 wave-issues per phase
    const long CC_BYTES = (long)B_ * HP_ * HP_ * 64;   // 1,183,744 B per cc

    // ---- per-thread A-fragment LDS byte offsets ---------------------------
    int lbase[4];
    #pragma unroll
    for (int mt = 0; mt < 4; ++mt) {
        int m  = m0 + wid * 64 + mt * 16 + l16;
        int gr = m / 56;
        int w  = m - gr * 56;
        lbase[mt] = (gr - gr0) * 4352 + w * 64 + quad * 16;
    }

    f32x4 acc[4][4];
    #pragma unroll
    for (int a = 0; a < 4; ++a)
        #pragma unroll
        for (int b2 = 0; b2 < 4; ++b2) acc[a][b2] = (f32x4){0.f, 0.f, 0.f, 0.f};

    bf16x8 Ar[2][4], Br[2][4];

    // A-stage for phase pp (cc = cc0+pp) into buffer pp&1; waves split issues.
#define STAGE(pp)                                                              \
    {                                                                          \
        const char* sA_ = xpb + (long)(cc0 + (pp)) * CC_BYTES + relA;          \
        const char* sB_ = xpb + (long)(cc0 + (pp)) * CC_BYTES + relB;          \
        char* dbase = &sAst[(pp) & 1][0];                                      \
        for (int q = wid; q < nTot; q += 4) {                                  \
            const char* sp; int d;                                             \
            if (q < nA) {                                                      \
                int off = q << 10;                                             \
                if (off + 1024 > bytesA) off = bytesA - 1024;                  \
                sp = sA_ + off; d = off;                                       \
            } else {                                                           \
                int off = (q - nA) << 10;                                      \
                if (off + 1024 > bytesB) off = bytesB - 1024;                  \
                sp = sB_ + off; d = bytesA + off;                              \
            }                                                                  \
            __builtin_amdgcn_global_load_lds(                                  \
                (gu32*)(sp + (long)lane * 16),                                 \
                (lu32*)(dbase + d), 16, 0, 0);                                 \
        }                                                                      \
    }

#define LOADB(slot, cc, j)                                                     \
    { _Pragma("unroll")                                                        \
      for (int nt = 0; nt < 4; ++nt)                                           \
          Br[slot][nt] = *(const bf16x8*)(wbs +                                \
              ((((long)(i * 7 + (j)) * 8 + (cc)) * 4 + nt) << 9) +             \
              (long)lane * 8); }

#define LDSA(slot, pp, j)                                                      \
    { const char* ab = &sAst[(pp) & 1][0];                                     \
      _Pragma("unroll")                                                        \
      for (int mt = 0; mt < 4; ++mt)                                           \
          Ar[slot][mt] = *(const bf16x8*)(ab + lbase[mt] + (j) * 128); }

    // prologue: issue phase-0 stage; the p=0 iteration's top-sync drains it
    STAGE(0)

    #pragma unroll
    for (int p = 0; p < 4; ++p) {
        const int cc = cc0 + p;

        // phase-top sync: DMA(p) had a full phase of cover (p=0: prologue).
        // vmcnt(0) waits own DMA issues; raw barrier makes all waves' DMA
        // visible. No drain of not-yet-issued DMA(p+1).
        asm volatile("s_waitcnt vmcnt(0)" ::: "memory");
        __builtin_amdgcn_s_barrier();

        if (p < 3) STAGE(p + 1)           // in flight across the whole phase

        LOADB(0, cc, 0)
        LOADB(1, cc, 1)
        LDSA(0, p, 0)

        #pragma unroll
        for (int j = 0; j < 7; ++j) {
            const int cs = j & 1;
            if (j < 6) LDSA((j + 1) & 1, p, j + 1)

            __builtin_amdgcn_s_setprio(1);
            #pragma unroll
            for (int mt = 0; mt < 4; ++mt)
                #pragma unroll
                for (int nt = 0; nt < 4; ++nt)
                    acc[mt][nt] = __builtin_amdgcn_mfma_f32_16x16x32_bf16(
                        Ar[cs][mt], Br[cs][nt], acc[mt][nt], 0, 0, 0);
            __builtin_amdgcn_s_setprio(0);

            if (j + 2 <= 6) LOADB(cs, cc, j + 2)
        }
        // no barrier here (moved to next phase top)
    }
#undef STAGE
#undef LOADB
#undef LDSA

    // Store bf16: C/D layout col(n)=lane&15, row(m)=quad*4+reg (validated)
    #pragma unroll
    for (int mt = 0; mt < 4; ++mt) {
        int mrow = m0 + wid * 64 + mt * 16 + quad * 4;
        #pragma unroll
        for (int nt = 0; nt < 4; ++nt) {
            int n = nt * 16 + l16;
            __hip_bfloat16* dst = kpart + ((long)slice * M_TOT + mrow) * NP + n;
            #pragma unroll
            for (int r = 0; r < 4; ++r)
                dst[(long)r * NP] = __float2bfloat16(acc[mt][nt][r]);
        }
    }
}

// R18: 8 pixels/wave vectorized fold (validated).
__global__ __launch_bounds__(256) void attn_fold3(const unsigned short* __restrict__ kpart,
                                                  const float* __restrict__ cb,
                                                  float* __restrict__ attnP)
{
    int tid  = threadIdx.x;
    int wid  = tid >> 6;
    int lane = tid & 63;
    int p0   = (blockIdx.x * 4 + wid) * 8;    // first of 8 pixels for this wave
    int sub  = lane >> 3;                     // pixel = p0 + sub
    int k    = lane & 7;                      // n = k*8 + j

    const short* kp = (const short*)kpart + (long)p0 * NP + lane * 8;
    float a8[8] = {0,0,0,0,0,0,0,0};
    #pragma unroll
    for (int sp = 0; sp < NSL; ++sp) {
        bf16x8 v = *(const bf16x8*)(kp + (long)sp * M_TOT * NP);
        #pragma unroll
        for (int j = 0; j < 8; ++j) {
            unsigned int u = (unsigned int)(unsigned short)v[j] << 16;
            a8[j] += __uint_as_float(u);
        }
    }

    const f32x4* cb4 = (const f32x4*)cb;
    f32x4 c0 = cb4[k * 2], c1 = cb4[k * 2 + 1];
    float lg[8];
    #pragma unroll
    for (int j = 0; j < 8; ++j) {
        float c = (j < 4) ? c0[j & 3] : c1[j & 3];
        lg[j] = (k * 8 + j < NT) ? (a8[j] + c) : -INFINITY;
    }
    float mx = lg[0];
    #pragma unroll
    for (int j = 1; j < 8; ++j) mx = fmaxf(mx, lg[j]);
    mx = fmaxf(mx, __shfl_xor(mx, 1, 64));
    mx = fmaxf(mx, __shfl_xor(mx, 2, 64));
    mx = fmaxf(mx, __shfl_xor(mx, 4, 64));

    float e[8]; float sum = 0.f;
    #pragma unroll
    for (int j = 0; j < 8; ++j) {
        e[j] = (k * 8 + j < NT) ? __expf(lg[j] - mx) : 0.f;
        sum += e[j];
    }
    sum += __shfl_xor(sum, 1, 64);
    sum += __shfl_xor(sum, 2, 64);
    sum += __shfl_xor(sum, 4, 64);
    float inv = 1.0f / sum;

    float* op = attnP + (long)(p0 + sub) * NT + k * 8;
    #pragma unroll
    for (int j = 0; j < 8; ++j)
        if (k * 8 + j < NT) op[j] = e[j] * inv;
}

// R18: out kernel with float4 staging and ONE barrier (validated).
__global__ __launch_bounds__(256) void out_kernel5(const float* __restrict__ x,
                                                   const float* __restrict__ attnP,
                                                   float* __restrict__ out)
{
    __shared__ float sX[7 * 4 * HP_ * 4]; // [i][cg4][wp][c4] 30.5 KB
    __shared__ float sA[56 * NT];         // [w][l] 10.7 KB

    int bid = blockIdx.x;                // < 3584
    int g   = bid & 7;                   // presumed XCD
    int s   = bid >> 3;                  // 0..447
    int bh  = g * 28 + (s % 28);         // 28 bh-rows per XCD slot
    int cg  = s / 28;                    // 0..15
    int b   = bh / H_;
    int h   = bh - b * H_;
    int c0  = cg * 16;
    int tid = threadIdx.x;

    // halo zero: cols wp in {0..5} u {62..67}, all 28 (i,cgr) rows (f32x4)
    {
        f32x4* sX4 = (f32x4*)sX;
        for (int idx = tid; idx < 28 * 12; idx += 256) {
            int row = idx / 12, t = idx - row * 12;
            int wp  = (t < 6) ? t : (t + 56);
            sX4[row * HP_ + wp] = (f32x4){0.f, 0.f, 0.f, 0.f};
        }
    }
    // attn stage: 686 float4 (base is 16B-aligned: 196*56 = 16*686)
    {
        const f32x4* ap4 = (const f32x4*)(attnP + ((size_t)(b * HW_) + h * W_) * NT);
        f32x4* sA4 = (f32x4*)sA;
        for (int idx = tid; idx < 686; idx += 256)
            sA4[idx] = ap4[idx];
    }
    // x stage: 16 ch x 14 float4 lanes; zero-fill invalid rows (no pre-zero)
    {
        int c  = tid >> 4;
        int wg = tid & 15;
        if (wg < 14) {
            const float* xc = x + (size_t)(b * C_ + c0 + c) * HW_;
            int cgr = c >> 2, ce = c & 3;
            #pragma unroll
            for (int i = 0; i < 7; ++i) {
                int ih = h + 2 * i - 6;
                f32x4 v = (f32x4){0.f, 0.f, 0.f, 0.f};
                if (ih >= 0 && ih < H_)
                    v = *(const f32x4*)(xc + (size_t)ih * W_ + wg * 4);
                float* dst = &sX[(((i * 4 + cgr) * HP_) + (wg * 4 + 6)) * 4 + ce];
                dst[0]  = v.x; dst[4]  = v.y;
                dst[8]  = v.z; dst[12] = v.w;
            }
        }
    }
    __syncthreads();

    int lane = tid & 63;
    int wid  = tid >> 6;                 // wave -> channels c0+wid*4 .. +3
    int w    = lane;
    bool active = (w < W_);
    int wc = active ? w : (W_ - 1);

    float aR[NT];
    #pragma unroll
    for (int l = 0; l < NT; ++l)
        aR[l] = sA[wc * NT + l];

    f32x4 acc = (f32x4){0.f, 0.f, 0.f, 0.f};
    #pragma unroll
    for (int i = 0; i < 7; ++i) {
        const float* sXi = &sX[(i * 4 + wid) * HP_ * 4];
        #pragma unroll
        for (int j = 0; j < 7; ++j) {
            f32x4 xv = *(const f32x4*)&sXi[(wc + 2 * j) * 4];
            float a = aR[i * 7 + j];
            acc.x += a * xv.x; acc.y += a * xv.y;
            acc.z += a * xv.z; acc.w += a * xv.w;
        }
    }

    if (active) {
        size_t o = ((size_t)(b * C_ + c0 + wid * 4)) * HW_ + h * W_ + w;
        out[o + 0 * HW_] = acc.x;
        out[o + 1 * HW_] = acc.y;
        out[o + 2 * HW_] = acc.z;
        out[o + 3 * HW_] = acc.w;
    }
}

// ===========================================================================
// FALLBACK PATH (R1, proven): used only if ws_size < fast-path need
// ===========================================================================
__global__ __launch_bounds__(256) void wt_kernel(const float* __restrict__ W1,
                                                 float* __restrict__ wT)
{
    int idx = blockIdx.x * 256 + threadIdx.x;
    int oc = idx & 127;
    int ct = idx >> 7;
    wT[idx] = W1[oc * (C_ * NT) + ct];
}

__global__ __launch_bounds__(256) void conv1_kernel(const float* __restrict__ x,
                                                    const float* __restrict__ wT,
                                                    const float* __restrict__ b1,
                                                    float* __restrict__ k)
{
    int tid = threadIdx.x;
    int w   = tid & 63;
    int ty  = tid >> 6;
    int h   = blockIdx.x * 4 + ty;
    int oc0 = blockIdx.y * 8;
    int b   = blockIdx.z;

    const float* xb = x + (size_t)b * C_ * HW_;
    float acc[8] = {0.f,0.f,0.f,0.f,0.f,0.f,0.f,0.f};

    for (int i = 0; i < 7; ++i) {
        int ih = h + 2 * i - 6;
        if (ih < 0 || ih >= H_) continue;
        for (int j = 0; j < 7; ++j) {
            int iw = w + 2 * j - 6;
            bool v  = (iw >= 0) && (iw < W_);
            float m = v ? 1.0f : 0.0f;
            const float* xr = xb + ih * W_ + (v ? iw : 0);
            const float* wr = wT + (size_t)(i * 7 + j) * OC1 + oc0;
            #pragma unroll 4
            for (int c = 0; c < C_; ++c) {
                float xv = m * xr[(size_t)c * HW_];
                const float4 w0 = *(const float4*)(wr + (size_t)c * NT * OC1);
                const float4 w1 = *(const float4*)(wr + (size_t)c * NT * OC1 + 4);
                acc[0] += xv * w0.x; acc[1] += xv * w0.y;
                acc[2] += xv * w0.z; acc[3] += xv * w0.w;
                acc[4] += xv * w1.x; acc[5] += xv * w1.y;
                acc[6] += xv * w1.z; acc[7] += xv * w1.w;
            }
        }
    }
    if (w < W_) {
        size_t o = ((size_t)(b * OC1 + oc0)) * HW_ + h * W_ + w;
        #pragma unroll
        for (int q = 0; q < 8; ++q)
            k[o + (size_t)q * HW_] = acc[q] + b1[oc0 + q];
    }
}

__global__ __launch_bounds__(256) void attn_kernel(const float* __restrict__ kin,
                                                   const float* __restrict__ W2,
                                                   const float* __restrict__ b2,
                                                   float* __restrict__ attn)
{
    __shared__ float sW2[128 * 49];
    int tid = threadIdx.x;
    for (int idx = tid; idx < 128 * 49; idx += 256) {
        int c = idx / 49, l = idx - c * 49;
        sW2[idx] = W2[l * 128 + c];
    }
    __syncthreads();

    int wid  = tid >> 6;
    int lane = tid & 63;
    int pix  = blockIdx.x * 4 + wid;
    int b    = pix / HW_;
    int hw   = pix - b * HW_;
    int l    = (lane < 49) ? lane : 0;

    const float* kb = kin + (size_t)b * OC1 * HW_ + hw;
    float acc = b2[l];
    #pragma unroll 8
    for (int c = 0; c < 128; ++c)
        acc += kb[(size_t)c * HW_] * sW2[c * 49 + l];

    float logit = (lane < 49) ? acc : -INFINITY;
    float mx = logit;
    for (int s = 32; s > 0; s >>= 1) mx = fmaxf(mx, __shfl_xor(mx, s, 64));
    float e = (lane < 49) ? __expf(logit - mx) : 0.0f;
    float sum = e;
    for (int s = 32; s > 0; s >>= 1) sum += __shfl_xor(sum, s, 64);
    if (lane < 49)
        attn[((size_t)b * NT + lane) * HW_ + hw] = e / sum;
}

__global__ __launch_bounds__(256) void out_kernel(const float* __restrict__ x,
                                                  const float* __restrict__ attn,
                                                  float* __restrict__ out)
{
    int idx = blockIdx.x * 256 + threadIdx.x;
    int w  = idx % 56;
    int t  = idx / 56;
    int h  = t % 56;
    int t2 = t / 56;
    int c  = t2 & 255;
    int b  = t2 >> 8;

    const float* xb = x + (size_t)(b * C_ + c) * HW_;
    const float* ab = attn + (size_t)b * NT * HW_ + h * W_ + w;

    float acc = 0.f;
    #pragma unroll
    for (int i = 0; i < 7; ++i) {
        int ih = h + 2 * i - 6;
        bool hv = (ih >= 0) && (ih < H_);
        #pragma unroll
        for (int j = 0; j < 7; ++j) {
            int iw = w + 2 * j - 6;
            bool v  = hv && (iw >= 0) && (iw < W_);
            float m = v ? 1.0f : 0.0f;
            int off = v ? (ih * W_ + iw) : 0;
            acc += (m * xb[off]) * ab[(size_t)(i * 7 + j) * HW_];
        }
    }
    out[idx] = acc;
}

// ===========================================================================
extern "C" void kernel_launch(void* const* d_in, const int* in_sizes, int n_in,
                              void* d_out, int out_size, void* d_ws, size_t ws_size,
                              hipStream_t stream)
{
    const float* x  = (const float*)d_in[0];
    const float* W1 = (const float*)d_in[1];
    const float* b1 = (const float*)d_in[2];
    const float* W2 = (const float*)d_in[3];
    const float* b2 = (const float*)d_in[4];
    float* out = (float*)d_out;

    // fast-path ws layout (bytes)
    const size_t xp_b    = (size_t)B_ * HP_ * HP_ * 256 * 2;        //  9,469,952
    const size_t wfb_b   = (size_t)NT * 8 * 4 * 64 * 8 * 2;         //  1,605,632
    const size_t kpart_b = (size_t)NSL * M_TOT * NP * 2;            // 22,478,848 (bf16)
    const size_t attn_b  = (size_t)M_TOT * NT * 4;                  //  2,458,624
    const size_t cb_b    = 256;
    const size_t need = xp_b + wfb_b + kpart_b + attn_b + cb_b;     // ~36.0 MB

    if (ws_size >= need) {
        char* base = (char*)d_ws;
        __hip_bfloat16* xp    = (__hip_bfloat16*)base;
        __hip_bfloat16* wfb   = (__hip_bfloat16*)(base + xp_b);
        __hip_bfloat16* kpart = (__hip_bfloat16*)(base + xp_b + wfb_b);
        float* attnP = (float*)(base + xp_b + wfb_b + kpart_b);
        float* cb    = (float*)(base + xp_b + wfb_b + kpart_b + attn_b);

        prep_kernel  <<<2568, 256, 0, stream>>>(x, W1, W2, b1, b2, xp, wfb, cb);
        conv1_mfma12 <<<784, 256, 0, stream>>>(xp, wfb, kpart);
        attn_fold3   <<<392, 256, 0, stream>>>((const unsigned short*)kpart, cb, attnP);
        out_kernel5  <<<3584, 256, 0, stream>>>(x, attnP, out);
    } else {
        // R1 fallback (~14.6 MB)
        float* wT   = (float*)d_ws;
        float* kbuf = wT + 1605632;
        float* attn = kbuf + 1605632;
        wt_kernel   <<<6272, 256, 0, stream>>>(W1, wT);
        conv1_kernel<<<dim3(14, 16, 4), 256, 0, stream>>>(x, wT, b1, kbuf);
        attn_kernel <<<3136, 256, 0, stream>>>(kbuf, W2, b2, attn);
        out_kernel  <<<12544, 256, 0, stream>>>(x, attn, out);
    }
}